// Round 12
// baseline (252.529 us; speedup 1.0000x reference)
//
#include <hip/hip_runtime.h>
#include <cmath>

typedef __attribute__((ext_vector_type(8)))  short short8;
typedef __attribute__((ext_vector_type(4)))  float f32x4;
typedef __attribute__((ext_vector_type(16))) float f32x16;

#define B_   32
#define C_   64
#define T_   8192
#define H_   256
#define TT   128
#define NTH  768             // 12 waves -> 3 waves/SIMD (latency hiding), 170 reg/wave budget

// LDS: ONE in-place buffer (rs1 -> rs2 -> rs3, barrier-separated) + xs.
//   buf row r as rs1 <-> t0-18+r (rows 0..145; conv2 reads rows 14..145)
//   buf row r as rs2 <-> t0-2+r  (rows 0..129)
//   buf row r as rs3 <-> t0+r    (rows 0..127 fp32)
//   xs  row r        <-> t0-19+r (rows 0..146 staged; 147..161 garbage pad, reads masked)
#define RS_ROWB 528
#define XS_ROWB 144
#define BUF_OFF 0            // 146 * 528 = 77088
#define XS_OFF  77088
#define LDS_BYTES (77088 + 162*144)   // 100416 -> 1 block/CU

// packed-A (32x32x16 frags): frag id = (tap*MT + mt)*KT + kt ; 1KB each
#define A1_SZ  98304         // 3*8*4
#define A2_SZ  393216        // 3*8*16
#define A3_SZ  196608        // 3*4*16
#define AW_TOTAL (A1_SZ + A2_SZ + A3_SZ)

__device__ __forceinline__ unsigned short f2bf(float f) {
    unsigned u = __builtin_bit_cast(unsigned, f);
    u += 0x7fffu + ((u >> 16) & 1u);
    return (unsigned short)(u >> 16);
}
__device__ __forceinline__ unsigned cvtpk(float lo, float hi) {
    unsigned r;
    asm("v_cvt_pk_bf16_f32 %0, %1, %2" : "=v"(r) : "v"(lo), "v"(hi));
    return r;
}

// ---- pack fp32 weights -> bf16 32x32x16 A-fragments ----
// lane l holds A[row = mt*32 + (l&31)][k = kt*16 + (l>>5)*8 + j]
__global__ void pack_w(const float* __restrict__ w1, const float* __restrict__ w2,
                       const float* __restrict__ w3, unsigned short* __restrict__ ws)
{
    int id = blockIdx.x * 256 + threadIdx.x;
    const float* w; int MT, KT, Cin; unsigned short* dst;
    if (id < 6144)       {             w = w1; MT = 8; KT = 4;  Cin = 64;  dst = ws; }
    else if (id < 30720) { id -= 6144; w = w2; MT = 8; KT = 16; Cin = 256; dst = ws + A1_SZ/2; }
    else if (id < 43008) { id -= 30720; w = w3; MT = 4; KT = 16; Cin = 256; dst = ws + (A1_SZ+A2_SZ)/2; }
    else return;
    const int lane = id & 63;
    int f = id >> 6;
    const int kt = f % KT; f /= KT;
    const int mt = f % MT;
    const int tap = f / MT;
    const int h  = mt*32 + (lane & 31);
    const int c0 = kt*16 + (lane >> 5)*8;
    unsigned short* o = dst + (size_t)id * 8;
    #pragma unroll
    for (int j = 0; j < 8; ++j)
        o[j] = f2bf(w[((size_t)(h*Cin + c0 + j))*3 + tap]);
}

__device__ __forceinline__ short8 ldA(const char* base, int frag, int lane) {
    return *(const short8*)(base + ((size_t)frag*64 + lane)*16);
}

__global__ __launch_bounds__(NTH, 3)
void arflow_mfma(const float* __restrict__ x,
                 const float* __restrict__ b_in, const float* __restrict__ b_mid,
                 const float* __restrict__ b_out,
                 const float* __restrict__ alpha, const float* __restrict__ beta,
                 const char* __restrict__ wpk,
                 float* __restrict__ out)
{
    __shared__ __align__(16) char lds[LDS_BYTES];
    unsigned short* xs = (unsigned short*)(lds + XS_OFF);
    char* buf = lds + BUF_OFF;

    const char* wA1 = wpk;
    const char* wA2 = wpk + A1_SZ;
    const char* wA3 = wpk + A1_SZ + A2_SZ;

    const int b   = blockIdx.y;
    const int t0  = blockIdx.x * TT;
    const int tid = threadIdx.x;
    const int lane = tid & 63;
    const int wid  = tid >> 6;          // 0..11
    const int l31 = lane & 31, l5 = lane >> 5;
    const int mg = wid & 3;             // Wm = 4
    const int ng = wid >> 2;            // Wn = 3 (0..2)

    // ---------------- stage x -> xs bf16 (rows 0..146); zero buf rows 0,1 ----------------
    {
        const int cg = tid / 192;       // 0..3 (16 ch each)
        const int tt = tid - cg*192;    // 0..191, coalesced along time
        if (tt < 147) {
            const int t = t0 - 19 + tt;
            #pragma unroll
            for (int p = 0; p < 8; ++p) {
                const int c = cg*16 + p*2;
                const float* xc0 = x + ((size_t)b*C_ + c)*T_;
                const float* xc1 = xc0 + T_;
                float v0 = 0.f, v1 = 0.f;
                if (t >= 0) { v0 = xc0[t]; v1 = xc1[t]; }
                *(unsigned*)(&xs[tt*72 + c]) = cvtpk(v0, v1);
            }
        }
        if (tid < 264) ((unsigned*)buf)[tid] = 0u;
    }
    __syncthreads();

    // ---- conv1: xs(64) -> rs1(256). mg: mts {2mg,2mg+1}; ng: nt {0,1}/{2,3}/{4}.
    //      KT = 12. A-ring depth 4, B-ring depth 2 ----
    {
        const int mt0 = mg*2;
        const int ntb = ng*2, ncnt = (ng == 2) ? 1 : 2;
        f32x16 acc[2][2];
        #pragma unroll
        for (int m = 0; m < 2; ++m) {
            f32x4 bq[4];
            #pragma unroll
            for (int q = 0; q < 4; ++q)
                bq[q] = *(const f32x4*)(b_in + (mt0+m)*32 + q*8 + l5*4);
            #pragma unroll
            for (int nt = 0; nt < 2; ++nt)
                #pragma unroll
                for (int q = 0; q < 4; ++q) {
                    acc[m][nt][4*q+0] = bq[q][0]; acc[m][nt][4*q+1] = bq[q][1];
                    acc[m][nt][4*q+2] = bq[q][2]; acc[m][nt][4*q+3] = bq[q][3];
                }
        }
        int nb[2];
        #pragma unroll
        for (int nt = 0; nt < 2; ++nt)
            nb[nt] = XS_OFF + (32*(ntb+nt) + l31)*XS_ROWB + l5*16;

        short8 Ar[4][2];
        short8 Br[2][2];
        #pragma unroll
        for (int k = 0; k < 3; ++k)
            #pragma unroll
            for (int m = 0; m < 2; ++m)
                Ar[k][m] = ldA(wA1, ((k>>2)*8 + mt0+m)*4 + (k&3), lane);
        #pragma unroll
        for (int nt = 0; nt < 2; ++nt) if (nt < ncnt)
            Br[0][nt] = *(const short8*)(lds + nb[nt]);
        #pragma unroll
        for (int kt = 0; kt < 12; ++kt) {
            if (kt + 3 < 12) {
                const int kn = kt + 3;
                #pragma unroll
                for (int m = 0; m < 2; ++m)
                    Ar[(kt+3)&3][m] = ldA(wA1, ((kn>>2)*8 + mt0+m)*4 + (kn&3), lane);
            }
            if (kt + 1 < 12) {
                const int kn = kt + 1, tapn = kn >> 2, ckn = kn & 3;
                #pragma unroll
                for (int nt = 0; nt < 2; ++nt) if (nt < ncnt)
                    Br[(kt+1)&1][nt] = *(const short8*)(lds + nb[nt] + tapn*XS_ROWB + ckn*32);
            }
            __builtin_amdgcn_s_setprio(1);
            #pragma unroll
            for (int nt = 0; nt < 2; ++nt) if (nt < ncnt)
                #pragma unroll
                for (int m = 0; m < 2; ++m)
                    acc[m][nt] = __builtin_amdgcn_mfma_f32_32x32x16_bf16(Ar[kt&3][m], Br[kt&1][nt], acc[m][nt], 0, 0, 0);
            __builtin_amdgcn_s_setprio(0);
        }
        #pragma unroll
        for (int nt = 0; nt < 2; ++nt) if (nt < ncnt) {
            const int rb = 2 + 32*(ntb+nt) + l31;    // rs1 row
            const int t  = t0 - 16 + 32*(ntb+nt) + l31;
            if (rb <= 145) {
                #pragma unroll
                for (int m = 0; m < 2; ++m) {
                    char* dst0 = buf + rb*RS_ROWB + (mt0+m)*64;
                    #pragma unroll
                    for (int q = 0; q < 4; ++q) {
                        unsigned long long pk = 0ull;
                        if (t >= 0)
                            pk = (unsigned long long)cvtpk(acc[m][nt][4*q+0], acc[m][nt][4*q+1])
                               | ((unsigned long long)cvtpk(acc[m][nt][4*q+2], acc[m][nt][4*q+3]) << 32);
                        *(unsigned long long*)(dst0 + q*16 + l5*8) = pk;
                    }
                }
            }
        }
    }
    __syncthreads();

    // ---- conv2: rs1 -> rs2 IN-PLACE. mts {2mg,2mg+1}; nt {0,1}/{2,3}/{4}. KT = 48 ----
    {
        const int mt0 = mg*2;
        const int ntb = ng*2, ncnt = (ng == 2) ? 1 : 2;
        f32x16 acc[2][2];
        #pragma unroll
        for (int m = 0; m < 2; ++m) {
            f32x4 bq[4];
            #pragma unroll
            for (int q = 0; q < 4; ++q)
                bq[q] = *(const f32x4*)(b_mid + (mt0+m)*32 + q*8 + l5*4);
            #pragma unroll
            for (int nt = 0; nt < 2; ++nt)
                #pragma unroll
                for (int q = 0; q < 4; ++q) {
                    acc[m][nt][4*q+0] = bq[q][0]; acc[m][nt][4*q+1] = bq[q][1];
                    acc[m][nt][4*q+2] = bq[q][2]; acc[m][nt][4*q+3] = bq[q][3];
                }
        }
        int nb[2];
        #pragma unroll
        for (int nt = 0; nt < 2; ++nt)
            nb[nt] = BUF_OFF + (14 + 32*(ntb+nt) + l31)*RS_ROWB + l5*16;

        short8 Ar[4][2];
        short8 Br[2][2];
        #pragma unroll
        for (int k = 0; k < 3; ++k) {
            const int tap = k >> 4, ck = k & 15;
            #pragma unroll
            for (int m = 0; m < 2; ++m)
                Ar[k][m] = ldA(wA2, (tap*8 + mt0+m)*16 + ck, lane);
        }
        #pragma unroll
        for (int nt = 0; nt < 2; ++nt) if (nt < ncnt)
            Br[0][nt] = *(const short8*)(lds + nb[nt]);
        #pragma unroll
        for (int kt = 0; kt < 48; ++kt) {
            if (kt + 3 < 48) {
                const int kn = kt + 3, tapn = kn >> 4, ckn = kn & 15;
                #pragma unroll
                for (int m = 0; m < 2; ++m)
                    Ar[(kt+3)&3][m] = ldA(wA2, (tapn*8 + mt0+m)*16 + ckn, lane);
            }
            if (kt + 1 < 48) {
                const int kn = kt + 1, tapn = kn >> 4, ckn = kn & 15;
                #pragma unroll
                for (int nt = 0; nt < 2; ++nt) if (nt < ncnt)
                    Br[(kt+1)&1][nt] = *(const short8*)(lds + nb[nt] + tapn*RS_ROWB + ckn*32);
            }
            __builtin_amdgcn_s_setprio(1);
            #pragma unroll
            for (int nt = 0; nt < 2; ++nt) if (nt < ncnt)
                #pragma unroll
                for (int m = 0; m < 2; ++m)
                    acc[m][nt] = __builtin_amdgcn_mfma_f32_32x32x16_bf16(Ar[kt&3][m], Br[kt&1][nt], acc[m][nt], 0, 0, 0);
            __builtin_amdgcn_s_setprio(0);
        }
        __syncthreads();                 // ALL rs1 reads done before in-place overwrite
        #pragma unroll
        for (int nt = 0; nt < 2; ++nt) if (nt < ncnt) {
            const int r2 = 32*(ntb+nt) + l31;        // rs2 row <-> t0-2+r2
            const int t  = t0 - 2 + r2;
            if (r2 <= 129) {
                #pragma unroll
                for (int m = 0; m < 2; ++m) {
                    char* dst0 = buf + r2*RS_ROWB + (mt0+m)*64;
                    #pragma unroll
                    for (int q = 0; q < 4; ++q) {
                        unsigned long long pk = 0ull;
                        if (t >= 0)
                            pk = (unsigned long long)cvtpk(acc[m][nt][4*q+0], acc[m][nt][4*q+1])
                               | ((unsigned long long)cvtpk(acc[m][nt][4*q+2], acc[m][nt][4*q+3]) << 32);
                        *(unsigned long long*)(dst0 + q*16 + l5*8) = pk;
                    }
                }
            }
        }
    }

    // ---- prefetch epilogue x into regs ----
    float xv[11];
    #pragma unroll
    for (int m = 0; m < 11; ++m) {
        const int e = tid + m*NTH;                   // 8192 = 64c * 128t
        if (e < 8192) {
            const int c = e >> 7, tl = e & 127;
            xv[m] = x[((size_t)b*C_ + c)*T_ + t0 + tl];
        }
    }
    __syncthreads();

    // ---- conv3: rs2 -> rs3(128, fp32) IN-PLACE. mt=mg; nt {0,1}/{2}/{3}. KT = 48 ----
    {
        const int mt = mg;
        const int ntb = (ng == 0) ? 0 : (ng + 1);    // 0 / 2 / 3
        const int ncnt = (ng == 0) ? 2 : 1;
        f32x4 bq[4];
        #pragma unroll
        for (int q = 0; q < 4; ++q)
            bq[q] = *(const f32x4*)(b_out + mt*32 + q*8 + l5*4);
        f32x16 acc[2];
        #pragma unroll
        for (int nt = 0; nt < 2; ++nt)
            #pragma unroll
            for (int q = 0; q < 4; ++q) {
                acc[nt][4*q+0] = bq[q][0]; acc[nt][4*q+1] = bq[q][1];
                acc[nt][4*q+2] = bq[q][2]; acc[nt][4*q+3] = bq[q][3];
            }
        int nb[2];
        #pragma unroll
        for (int nt = 0; nt < 2; ++nt)
            nb[nt] = BUF_OFF + (32*(ntb+nt) + l31)*RS_ROWB + l5*16;

        short8 Ar[6];
        short8 Br[2][2];
        #pragma unroll
        for (int k = 0; k < 5; ++k) {
            const int tap = k >> 4, ck = k & 15;
            Ar[k] = ldA(wA3, (tap*4 + mt)*16 + ck, lane);
        }
        #pragma unroll
        for (int nt = 0; nt < 2; ++nt) if (nt < ncnt)
            Br[0][nt] = *(const short8*)(lds + nb[nt]);
        #pragma unroll
        for (int kt = 0; kt < 48; ++kt) {
            if (kt + 5 < 48) {
                const int kn = kt + 5, tapn = kn >> 4, ckn = kn & 15;
                Ar[(kt+5)%6] = ldA(wA3, (tapn*4 + mt)*16 + ckn, lane);
            }
            if (kt + 1 < 48) {
                const int kn = kt + 1, tapn = kn >> 4, ckn = kn & 15;
                #pragma unroll
                for (int nt = 0; nt < 2; ++nt) if (nt < ncnt)
                    Br[(kt+1)&1][nt] = *(const short8*)(lds + nb[nt] + tapn*RS_ROWB + ckn*32);
            }
            __builtin_amdgcn_s_setprio(1);
            #pragma unroll
            for (int nt = 0; nt < 2; ++nt) if (nt < ncnt)
                acc[nt] = __builtin_amdgcn_mfma_f32_32x32x16_bf16(Ar[kt%6], Br[kt&1][nt], acc[nt], 0, 0, 0);
            __builtin_amdgcn_s_setprio(0);
        }
        __syncthreads();                 // ALL rs2 reads done before fp32 overwrite
        #pragma unroll
        for (int nt = 0; nt < 2; ++nt) if (nt < ncnt) {
            const int row = 32*(ntb+nt) + l31;       // rs3 <-> t0+row
            char* dst0 = buf + row*RS_ROWB + mt*128;
            #pragma unroll
            for (int q = 0; q < 4; ++q) {
                f32x4 v;
                v[0] = acc[nt][4*q+0]; v[1] = acc[nt][4*q+1];
                v[2] = acc[nt][4*q+2]; v[3] = acc[nt][4*q+3];
                *(f32x4*)(dst0 + q*32 + l5*16) = v;
            }
        }
    }
    __syncthreads();

    // ---- epilogue: z = exp(alpha*tanh(log_s)+beta)*x + t ----
    {
        const float* rs3f = (const float*)buf;       // [128 rows][132 floats]
        #pragma unroll
        for (int m = 0; m < 11; ++m) {
            const int e = tid + m*NTH;
            if (e < 8192) {
                const int c = e >> 7, tl = e & 127;
                const float ls = rs3f[tl*132 + c];
                const float tv = rs3f[tl*132 + c + 64];
                const float e2 = __expf(2.f * ls);
                const float th = fmaf(-2.f, __builtin_amdgcn_rcpf(e2 + 1.f), 1.f);
                const float lsv = fmaf(alpha[c], th, beta[c]);
                out[((size_t)b*C_ + c)*T_ + t0 + tl] = fmaf(__expf(lsv), xv[m], tv);
            }
        }
    }
}

extern "C" void kernel_launch(void* const* d_in, const int* in_sizes, int n_in,
                              void* d_out, int out_size, void* d_ws, size_t ws_size,
                              hipStream_t stream) {
    const float* x     = (const float*)d_in[0];
    const float* w_in  = (const float*)d_in[1];
    const float* b_in  = (const float*)d_in[2];
    const float* w_mid = (const float*)d_in[3];
    const float* b_mid = (const float*)d_in[4];
    const float* w_out = (const float*)d_in[5];
    const float* b_out = (const float*)d_in[6];
    const float* alpha = (const float*)d_in[7];
    const float* beta  = (const float*)d_in[8];
    float* out = (float*)d_out;

    if (ws_size < (size_t)AW_TOTAL) return;

    hipLaunchKernelGGL(pack_w, dim3(168), dim3(256), 0, stream,
                       w_in, w_mid, w_out, (unsigned short*)d_ws);
    hipLaunchKernelGGL(arflow_mfma, dim3(T_/TT, B_), dim3(NTH), 0, stream,
                       x, b_in, b_mid, b_out, alpha, beta, (const char*)d_ws, out);
}